// Round 8
// baseline (455.220 us; speedup 1.0000x reference)
//
#include <hip/hip_runtime.h>
#include <hip/hip_bf16.h>
#include <hip/hip_cooperative_groups.h>
#include <cstdint>
#include <cstddef>

namespace cg = cooperative_groups;

// Problem constants
#define EE    1024
#define DIN   2048
#define NST   16
#define DTR   64
#define BB_   2
#define LL    1024
#define BL    (BB_*LL)        // 2048 tokens
#define NCHUNK 32             // standalone scan path
#define CLEN   32
#define NCHUNK_C 16           // cooperative path (256 blocks)
#define CLEN_C   64
#define RTT   16              // TT rank (all four factor pairs)

typedef unsigned short u16;
typedef unsigned int   u32;

// ---------------- workspace layout (in floats) ----------------
static constexpr size_t OFF_WINT  = 0;                   // bf16 [4096][1024]
static constexpr size_t OFF_WOUTT = 2097152;             // bf16 [1024][2048]
static constexpr size_t OFF_WXT   = 3145728;             // bf16 [128][2048] rows>=96 zero
static constexpr size_t OFF_WDTT  = 3276800;             // bf16 [2048][64]
static constexpr size_t OFF_A2T   = 3342336;             // f32  [16][2048]
static constexpr size_t OFF_XB    = 3375104;             // bf16 [2048][1024]
static constexpr size_t OFF_XZB   = 4423680;             // bf16 [2048][4096]
static constexpr size_t OFF_YB    = 8617984;             // bf16 [2048][2048]
static constexpr size_t OFF_PART  = 10715136;            // f32  [16][2048][128] ; reused: GEMM4 partials [2][2048][1024]
static constexpr size_t OFF_DTBC  = 14909440;            // f32  [2048][96]
static constexpr size_t OFF_DTUNB = 15106048;            // bf16 [2048][64]
static constexpr size_t OFF_DTB   = 15171584;            // bf16 [2048][2048] (dt)
static constexpr size_t OFF_YSB   = 17268736;            // bf16 [2048][2048]
static constexpr size_t OFF_HC    = 19365888;            // f32  [2*32][16][2048] carries (coop uses half)
static constexpr size_t OFF_SDT   = 21463040;            // f32  [2*32][2048]

// ---------------- helpers ----------------
__device__ __forceinline__ u16 f2bf(float f) {   // RNE f32->bf16
    u32 u = __float_as_uint(f);
    u += 0x7fffu + ((u >> 16) & 1u);
    return (u16)(u >> 16);
}
__device__ __forceinline__ float bf2f(u16 v) {
    return __uint_as_float((u32)v << 16);
}

__device__ __forceinline__ void async_copy16(const void* g, void* l) {
    __builtin_amdgcn_global_load_lds((const __attribute__((address_space(1))) u32*)g,
                                     (__attribute__((address_space(3))) u32*)l,
                                     16, 0, 0);
}

__device__ __forceinline__ float softplusf(float v) {
    return fmaxf(v, 0.f) + log1pf(__expf(-fabsf(v)));
}

// ---------------- fused prep: 4 TT builds + x->bf16 + A2t ----------------
__device__ void tt_part(const float* __restrict__ g1, const float* __restrict__ g2,
                        u16* __restrict__ Wt, int m1, int n1, int m2, int n2,
                        int c, int crows, float* g1col, float* g2col)
{
    const int rowsW = m1 * m2;
    if (c >= crows) {                      // zero padding rows (GEMM2 N-pad)
        for (int k = threadIdx.x; k < rowsW; k += 256)
            Wt[(size_t)c * rowsW + k] = 0;
        return;
    }
    const int i = c / n2;
    const int j = c - i * n2;

    for (int e = threadIdx.x; e < m1 * RTT; e += 256) {
        const int a = e >> 4, rr = e & 15;
        g1col[e] = g1[(size_t)(a * n1 + i) * RTT + rr];
    }
    for (int e = threadIdx.x; e < RTT * m2; e += 256) {
        const int rr = e / m2, bb = e - rr * m2;
        g2col[e] = g2[(size_t)(rr * m2 + bb) * n2 + j];
    }
    __syncthreads();

    for (int k = threadIdx.x; k < rowsW; k += 256) {
        const int a  = k / m2;
        const int bb = k - a * m2;
        const float* gp = g1col + a * RTT;
        float s = 0.f;
        #pragma unroll
        for (int rr = 0; rr < RTT; ++rr)
            s = fmaf(gp[rr], g2col[rr * m2 + bb], s);
        Wt[(size_t)c * rowsW + k] = f2bf(s);
    }
}

__global__ __launch_bounds__(256) void mega_prep(
    const float* __restrict__ in_g1, const float* __restrict__ in_g2, u16* __restrict__ W_inT,
    const float* __restrict__ out_g1, const float* __restrict__ out_g2, u16* __restrict__ W_outT,
    const float* __restrict__ x_g1, const float* __restrict__ x_g2, u16* __restrict__ W_xT,
    const float* __restrict__ dt_g1, const float* __restrict__ dt_g2, u16* __restrict__ W_dtT,
    const float* __restrict__ x, u16* __restrict__ xb,
    const float* __restrict__ A_log, float* __restrict__ A2t)
{
    __shared__ float g1col[32 * RTT];
    __shared__ float g2col[RTT * 64];
    const int blk = blockIdx.x;
    if (blk < 4096) {
        tt_part(in_g1, in_g2, W_inT, 32, 64, 32, 64, blk, 4096, g1col, g2col);
    } else if (blk < 5120) {
        tt_part(out_g1, out_g2, W_outT, 32, 32, 64, 32, blk - 4096, 1024, g1col, g2col);
    } else if (blk < 5248) {
        tt_part(x_g1, x_g2, W_xT, 32, 8, 64, 12, blk - 5120, 96, g1col, g2col);
    } else if (blk < 7296) {
        tt_part(dt_g1, dt_g2, W_dtT, 8, 32, 8, 64, blk - 5248, 2048, g1col, g2col);
    } else if (blk < 9344) {
        const int i = (blk - 7296) * 256 + threadIdx.x;   // over BL*EE/4
        float4 v = ((const float4*)x)[i];
        ushort4 o;
        o.x = f2bf(v.x); o.y = f2bf(v.y); o.z = f2bf(v.z); o.w = f2bf(v.w);
        ((ushort4*)xb)[i] = o;
    } else {
        const int idx = (blk - 9344) * 256 + threadIdx.x; // over DIN*NST
        const int d = idx >> 4, n = idx & 15;
        A2t[n * DIN + d] = -expf(A_log[idx]);
    }
}

// ---------------- bf16 MFMA GEMM (templated BN / BK / output mode) ----------------
typedef __attribute__((ext_vector_type(8))) short bf16x8;
typedef __attribute__((ext_vector_type(4))) float floatx4;

template<int BN, int BK, int OUT>
__global__ __launch_bounds__(256) void gemm_bf16(
    const u16* __restrict__ A, const u16* __restrict__ Bt, void* __restrict__ Cout,
    int K, int ldc, int kchunk, size_t czstride)
{
    constexpr int BM   = 128;
    constexpr int NT   = BN / 32;
    constexpr int SLOT = BK / 8;
    constexpr int CR   = 64 / SLOT;
    constexpr int NACH = BM / CR / 4;
    constexpr int NBCH = BN / CR / 4;
    constexpr int KG   = BK / 32;
    __shared__ u16 As[BM * BK];
    __shared__ u16 Bs[BN * BK];

    const int tid  = threadIdx.x;
    const int w    = tid >> 6;
    const int lane = tid & 63;
    const int wm   = w & 1, wn = w >> 1;
    const int row0 = blockIdx.y * BM;
    const int col0 = blockIdx.x * BN;
    const int kbeg = blockIdx.z * kchunk;

    const int srow = lane / SLOT;
    const int kqp  = lane % SLOT;
    const u16* ga[NACH]; u16* la[NACH];
    #pragma unroll
    for (int i = 0; i < NACH; ++i) {
        const int c  = w * NACH + i;
        const int r  = c * CR + srow;
        const int kq = kqp ^ ((r >> 1) & (SLOT - 1));
        ga[i] = A + (size_t)(row0 + r) * K + kbeg + kq * 8;
        la[i] = &As[c * CR * BK];
    }
    const u16* gb[NBCH]; u16* lb[NBCH];
    #pragma unroll
    for (int i = 0; i < NBCH; ++i) {
        const int c  = w * NBCH + i;
        const int r  = c * CR + srow;
        const int kq = kqp ^ ((r >> 1) & (SLOT - 1));
        gb[i] = Bt + (size_t)(col0 + r) * K + kbeg + kq * 8;
        lb[i] = &Bs[c * CR * BK];
    }

    const int q = lane >> 4, l15 = lane & 15;
    int a_off[4][KG], b_off[NT][KG];
    #pragma unroll
    for (int mt = 0; mt < 4; ++mt) {
        const int r = wm * 64 + mt * 16 + l15;
        const int m = (r >> 1) & (SLOT - 1);
        #pragma unroll
        for (int kk = 0; kk < KG; ++kk)
            a_off[mt][kk] = r * BK + ((kk * 4 + q) ^ m) * 8;
    }
    #pragma unroll
    for (int nt = 0; nt < NT; ++nt) {
        const int r = wn * (BN / 2) + nt * 16 + l15;
        const int m = (r >> 1) & (SLOT - 1);
        #pragma unroll
        for (int kk = 0; kk < KG; ++kk)
            b_off[nt][kk] = r * BK + ((kk * 4 + q) ^ m) * 8;
    }

    floatx4 acc[4][NT];
    #pragma unroll
    for (int mt = 0; mt < 4; ++mt)
        #pragma unroll
        for (int nt = 0; nt < NT; ++nt)
            acc[mt][nt] = (floatx4){0.f, 0.f, 0.f, 0.f};

    for (int k0 = 0; k0 < kchunk; k0 += BK) {
        #pragma unroll
        for (int i = 0; i < NACH; ++i) { async_copy16(ga[i], la[i]); ga[i] += BK; }
        #pragma unroll
        for (int i = 0; i < NBCH; ++i) { async_copy16(gb[i], lb[i]); gb[i] += BK; }
        __syncthreads();

        bf16x8 af[4][KG], bfv[NT][KG];
        #pragma unroll
        for (int mt = 0; mt < 4; ++mt)
            #pragma unroll
            for (int kk = 0; kk < KG; ++kk)
                af[mt][kk] = *(const bf16x8*)&As[a_off[mt][kk]];
        #pragma unroll
        for (int nt = 0; nt < NT; ++nt)
            #pragma unroll
            for (int kk = 0; kk < KG; ++kk)
                bfv[nt][kk] = *(const bf16x8*)&Bs[b_off[nt][kk]];

        #pragma unroll
        for (int kk = 0; kk < KG; ++kk)
            #pragma unroll
            for (int mt = 0; mt < 4; ++mt)
                #pragma unroll
                for (int nt = 0; nt < NT; ++nt)
                    acc[mt][nt] = __builtin_amdgcn_mfma_f32_16x16x32_bf16(
                        af[mt][kk], bfv[nt][kk], acc[mt][nt], 0, 0, 0);

        __syncthreads();
    }

    // epilogue: C/D layout col=lane&15, row=(lane>>4)*4+reg  [verified m89/m91]
    #pragma unroll
    for (int mt = 0; mt < 4; ++mt) {
        const int row = row0 + wm * 64 + mt * 16 + q * 4;
        #pragma unroll
        for (int nt = 0; nt < NT; ++nt) {
            const int col = col0 + wn * (BN / 2) + nt * 16 + l15;
            #pragma unroll
            for (int r = 0; r < 4; ++r) {
                const float v = acc[mt][nt][r];
                if constexpr (OUT == 0) {
                    ((float*)Cout)[(size_t)blockIdx.z * czstride + (size_t)(row + r) * ldc + col] = v;
                } else if constexpr (OUT == 1) {
                    ((u16*)Cout)[(size_t)(row + r) * ldc + col] = f2bf(v);
                } else {
                    ((u16*)Cout)[(size_t)(row + r) * ldc + col] = f2bf(softplusf(v));
                }
            }
        }
    }
}

// reduce GEMM2 split-K partials (fallback path)
__global__ __launch_bounds__(256) void reduce_dtbc(
    const float* __restrict__ part, float* __restrict__ dtBC, u16* __restrict__ dtun_b)
{
    int idx = blockIdx.x * 256 + threadIdx.x;
    if (idx >= BL * 96) return;
    const int row = idx / 96;
    const int col = idx - row * 96;
    float s = 0.f;
    #pragma unroll
    for (int z = 0; z < 16; ++z)
        s += part[(size_t)z * BL * 128 + (size_t)row * 128 + col];
    dtBC[idx] = s;
    if (col < 64) dtun_b[(size_t)row * 64 + col] = f2bf(s);
}

// reduce GEMM4 split-K partials (z=2) -> f32 d_out, float4-wide
__global__ __launch_bounds__(256) void reduce_out(
    const float* __restrict__ part, float* __restrict__ out)
{
    const int idx = blockIdx.x * 256 + threadIdx.x;   // over BL*EE/4
    const float4 a = ((const float4*)part)[idx];
    const float4 b = ((const float4*)part)[idx + BL * EE / 4];
    float4 o;
    o.x = a.x + b.x; o.y = a.y + b.y; o.z = a.z + b.z; o.w = a.w + b.w;
    ((float4*)out)[idx] = o;
}

// ---------------- conv (depthwise K=4, SAME pad_lo=1) + SiLU + gate, bf16, 8-wide ----------------
typedef __attribute__((ext_vector_type(8))) unsigned short ushortx8;

__global__ __launch_bounds__(256) void conv_gate(
    const u16* __restrict__ xzb, const float* __restrict__ filt,
    const float* __restrict__ bias, u16* __restrict__ yb)
{
    int idx = blockIdx.x * blockDim.x + threadIdx.x;   // over BL*DIN/8
    if (idx >= BL * DIN / 8) return;
    const int d  = (idx % (DIN / 8)) * 8;
    const int bt = idx / (DIN / 8);
    const int b  = bt >> 10;
    const int t  = bt & 1023;

    float acc[8];
    #pragma unroll
    for (int j = 0; j < 8; ++j) acc[j] = bias[d + j];
    #pragma unroll
    for (int k = 0; k < 4; ++k) {
        const int tt = t + k - 1;
        if ((unsigned)tt < (unsigned)LL) {
            const ushortx8 xc = *(const ushortx8*)(xzb + (size_t)(b * LL + tt) * (2 * DIN) + d);
            #pragma unroll
            for (int j = 0; j < 8; ++j)
                acc[j] = fmaf(bf2f(xc[j]), filt[(size_t)k * DIN + d + j], acc[j]);
        }
    }
    const ushortx8 z = *(const ushortx8*)(xzb + (size_t)bt * (2 * DIN) + DIN + d);
    ushortx8 o;
    #pragma unroll
    for (int j = 0; j < 8; ++j)
        o[j] = f2bf(acc[j] / (1.f + __expf(-acc[j])) * bf2f(z[j]));
    *(ushortx8*)(yb + (size_t)bt * DIN + d) = o;
}

// ---------------- standalone SSM scan (fallback path, NCHUNK=32) ----------------
__global__ __launch_bounds__(256) void scan_phase_a(
    const u16* __restrict__ dt, const u16* __restrict__ u,
    const float* __restrict__ dtBC, const float* __restrict__ A2t,
    float* __restrict__ hend, float* __restrict__ sdtbuf)
{
    const int d = blockIdx.x * 256 + threadIdx.x;
    const int c = blockIdx.y;
    const int b = blockIdx.z;

    __shared__ float Bs[CLEN][NST];
    for (int e = threadIdx.x; e < CLEN * NST; e += 256) {
        const int tl = e >> 4, n = e & 15;
        Bs[tl][n] = dtBC[(size_t)(b * LL + c * CLEN + tl) * 96 + 64 + n];
    }
    __syncthreads();

    float A2r[NST];
    #pragma unroll
    for (int n = 0; n < NST; ++n) A2r[n] = A2t[n * DIN + d];

    float h[NST] = {};
    float sdt = 0.f;
    const size_t tbase = (size_t)(b * LL + c * CLEN) * DIN + d;
    for (int tl = 0; tl < CLEN; ++tl) {
        const float dtv = bf2f(dt[tbase + (size_t)tl * DIN]);
        const float uv  = bf2f(u [tbase + (size_t)tl * DIN]);
        sdt += dtv;
        const float cu = dtv * uv;
        #pragma unroll
        for (int n = 0; n < NST; ++n) {
            const float a = __expf(A2r[n] * dtv);
            h[n] = fmaf(a, h[n], cu * Bs[tl][n]);
        }
    }
    const int cb = b * NCHUNK + c;
    #pragma unroll
    for (int n = 0; n < NST; ++n)
        hend[((size_t)cb * NST + n) * DIN + d] = h[n];
    sdtbuf[(size_t)cb * DIN + d] = sdt;
}

__global__ __launch_bounds__(256) void scan_phase_b(
    const float* __restrict__ A2t, const float* __restrict__ sdtbuf,
    float* __restrict__ hcarry)
{
    const int idx = blockIdx.x * 256 + threadIdx.x;
    if (idx >= BB_ * NST * DIN) return;
    const int d = idx & (DIN - 1);
    const int n = (idx >> 11) & 15;
    const int b = idx >> 15;
    const float A2 = A2t[n * DIN + d];
    float h = 0.f;
    for (int c = 0; c < NCHUNK; ++c) {
        const int cb = b * NCHUNK + c;
        const size_t off = ((size_t)cb * NST + n) * DIN + d;
        const float he = hcarry[off];
        const float pa = __expf(A2 * sdtbuf[(size_t)cb * DIN + d]);
        hcarry[off] = h;
        h = fmaf(pa, h, he);
    }
}

__global__ __launch_bounds__(256) void scan_phase_c(
    const u16* __restrict__ dt, const u16* __restrict__ u,
    const float* __restrict__ dtBC, const float* __restrict__ A2t,
    const float* __restrict__ hinit, const float* __restrict__ Dp,
    u16* __restrict__ ysb)
{
    const int d = blockIdx.x * 256 + threadIdx.x;
    const int c = blockIdx.y;
    const int b = blockIdx.z;

    __shared__ float Bs[CLEN][NST];
    __shared__ float Cs[CLEN][NST];
    for (int e = threadIdx.x; e < CLEN * NST; e += 256) {
        const int tl = e >> 4, n = e & 15;
        const size_t base = (size_t)(b * LL + c * CLEN + tl) * 96;
        Bs[tl][n] = dtBC[base + 64 + n];
        Cs[tl][n] = dtBC[base + 80 + n];
    }
    __syncthreads();

    float A2r[NST], h[NST];
    const int cb = b * NCHUNK + c;
    #pragma unroll
    for (int n = 0; n < NST; ++n) {
        A2r[n] = A2t[n * DIN + d];
        h[n]   = hinit[((size_t)cb * NST + n) * DIN + d];
    }
    const float Dv = Dp[d];

    const size_t tbase = (size_t)(b * LL + c * CLEN) * DIN + d;
    for (int tl = 0; tl < CLEN; ++tl) {
        const float dtv = bf2f(dt[tbase + (size_t)tl * DIN]);
        const float uv  = bf2f(u [tbase + (size_t)tl * DIN]);
        const float cu = dtv * uv;
        float yacc = 0.f;
        #pragma unroll
        for (int n = 0; n < NST; ++n) {
            const float a = __expf(A2r[n] * dtv);
            h[n] = fmaf(a, h[n], cu * Bs[tl][n]);
            yacc = fmaf(h[n], Cs[tl][n], yacc);
        }
        ysb[tbase + (size_t)tl * DIN] = f2bf(fmaf(Dv, uv, yacc));
    }
}

// ---------------- cooperative mid-section (256 blocks x 256 threads) ----------------
// P0 reduce; P1 GEMM3 (128x128 tiles = 256 blocks); P2 scan_a (NCHUNK_C=16,
// CLEN_C=64, dt cached in LDS); P3 carry scan; P4 replay -> ysb.
struct CoopShm {
    union {
        struct { u16 As[128 * 64]; u16 Bs[128 * 64]; } g;                // 32 KB (P1)
        struct { float Bsc[CLEN_C][NST]; float Csc[CLEN_C][NST];
                 u16 dtc[CLEN_C * 256]; } s;                             // 40 KB (P2/P4)
    };
};

__global__ __launch_bounds__(256) void coop_mid(
    const float* __restrict__ part, float* __restrict__ dtBC, u16* __restrict__ dtun_b,
    const u16* __restrict__ W_dtT, u16* __restrict__ dtb,
    const u16* __restrict__ yb, const float* __restrict__ A2t,
    float* __restrict__ hc, float* __restrict__ sdtg,
    const float* __restrict__ Dp, u16* __restrict__ ysb)
{
    __shared__ CoopShm shm;
    cg::grid_group grid = cg::this_grid();
    const int blk = blockIdx.x;
    const int tid = threadIdx.x;

    // ---- P0: reduce GEMM2 split-K partials (768 items/block) ----
    #pragma unroll
    for (int e = 0; e < 3; ++e) {
        const int idx = blk * 768 + e * 256 + tid;
        const int row = idx / 96;
        const int col = idx - row * 96;
        float s = 0.f;
        #pragma unroll
        for (int z = 0; z < 16; ++z)
            s += part[(size_t)z * BL * 128 + (size_t)row * 128 + col];
        dtBC[idx] = s;
        if (col < 64) dtun_b[(size_t)row * 64 + col] = f2bf(s);
    }
    __threadfence();
    grid.sync();

    // ---- P1: GEMM3 dt = softplus(dt_un @ W_dt^T), BM=128 BN=128 K=64 ----
    {
        constexpr int BK = 64, SLOT = 8, CR = 8;
        const int row0 = (blk >> 4) * 128;
        const int col0 = (blk & 15) * 128;
        const int w    = tid >> 6;
        const int lane = tid & 63;
        const int wm   = w & 1, wn = w >> 1;
        const int srow = lane / SLOT;
        const int kqp  = lane % SLOT;

        #pragma unroll
        for (int i = 0; i < 4; ++i) {            // A: 128 rows
            const int c  = w * 4 + i;
            const int r  = c * CR + srow;
            const int kq = kqp ^ ((r >> 1) & (SLOT - 1));
            async_copy16(dtun_b + (size_t)(row0 + r) * 64 + kq * 8, &shm.g.As[c * CR * BK]);
        }
        #pragma unroll
        for (int i = 0; i < 4; ++i) {            // B: 128 rows
            const int c  = w * 4 + i;
            const int r  = c * CR + srow;
            const int kq = kqp ^ ((r >> 1) & (SLOT - 1));
            async_copy16(W_dtT + (size_t)(col0 + r) * 64 + kq * 8, &shm.g.Bs[c * CR * BK]);
        }
        __syncthreads();

        const int q = lane >> 4, l15 = lane & 15;
        floatx4 acc[4][4];
        #pragma unroll
        for (int mt = 0; mt < 4; ++mt)
            #pragma unroll
            for (int nt = 0; nt < 4; ++nt)
                acc[mt][nt] = (floatx4){0.f, 0.f, 0.f, 0.f};

        #pragma unroll
        for (int kk = 0; kk < 2; ++kk) {
            bf16x8 af[4], bfv[4];
            #pragma unroll
            for (int mt = 0; mt < 4; ++mt) {
                const int r = wm * 64 + mt * 16 + l15;
                af[mt] = *(const bf16x8*)&shm.g.As[r * BK + (((kk * 4 + q) ^ ((r >> 1) & 7)) * 8)];
            }
            #pragma unroll
            for (int nt = 0; nt < 4; ++nt) {
                const int r = wn * 64 + nt * 16 + l15;
                bfv[nt] = *(const bf16x8*)&shm.g.Bs[r * BK + (((kk * 4 + q) ^ ((r >> 1) & 7)) * 8)];
            }
            #pragma unroll
            for (int mt = 0; mt < 4; ++mt)
                #pragma unroll
                for (int nt = 0; nt < 4; ++nt)
                    acc[mt][nt] = __builtin_amdgcn_mfma_f32_16x16x32_bf16(
                        af[mt], bfv[nt], acc[mt][nt], 0, 0, 0);
        }

        #pragma unroll
        for (int mt = 0; mt < 4; ++mt) {
            const int row = row0 + wm * 64 + mt * 16 + q * 4;
            #pragma unroll
            for (int nt = 0; nt < 4; ++nt) {
                const int col = col0 + wn * 64 + nt * 16 + l15;
                #pragma unroll
                for (int r = 0; r < 4; ++r)
                    dtb[(size_t)(row + r) * DIN + col] = f2bf(softplusf(acc[mt][nt][r]));
            }
        }
    }
    __threadfence();
    grid.sync();

    // ---- block mapping for scan phases: 8 d-blocks x 16 chunks x 2 batches ----
    const int db = blk & 7;
    const int c  = (blk >> 3) & 15;
    const int b  = blk >> 7;
    const int d  = db * 256 + tid;
    const int cb = b * NCHUNK_C + c;
    const size_t tbase = (size_t)(b * LL + c * CLEN_C) * DIN + d;

    float A2r[NST];
    #pragma unroll
    for (int n = 0; n < NST; ++n) A2r[n] = A2t[n * DIN + d];

    // ---- P2: stage B/C + dt cache, chunk-local scan from h=0 ----
    {
        for (int e = tid; e < CLEN_C * NST; e += 256) {
            const int tl = e >> 4, n = e & 15;
            const size_t base = (size_t)(b * LL + c * CLEN_C + tl) * 96;
            shm.s.Bsc[tl][n] = dtBC[base + 64 + n];
            shm.s.Csc[tl][n] = dtBC[base + 80 + n];
        }
        for (int tl = 0; tl < CLEN_C; ++tl)
            shm.s.dtc[tl * 256 + tid] = dtb[tbase + (size_t)tl * DIN];
        __syncthreads();

        float h[NST] = {};
        float sdt = 0.f;
        for (int tl = 0; tl < CLEN_C; ++tl) {
            const float dtv = bf2f(shm.s.dtc[tl * 256 + tid]);
            const float uv  = bf2f(yb[tbase + (size_t)tl * DIN]);
            sdt += dtv;
            const float cu = dtv * uv;
            #pragma unroll
            for (int n = 0; n < NST; ++n) {
                const float a = __expf(A2r[n] * dtv);
                h[n] = fmaf(a, h[n], cu * shm.s.Bsc[tl][n]);
            }
        }
        #pragma unroll
        for (int n = 0; n < NST; ++n)
            hc[((size_t)cb * NST + n) * DIN + d] = h[n];
        sdtg[(size_t)cb * DIN + d] = sdt;
    }
    __threadfence();
    grid.sync();

    // ---- P3: scan the 16 chunk carries (65536 items, 256/block) ----
    {
        const int idx = blk * 256 + tid;         // b*32768 + n*2048 + d
        const int dd = idx & (DIN - 1);
        const int nn = (idx >> 11) & 15;
        const int bb = idx >> 15;
        const float A2 = A2t[nn * DIN + dd];
        float h = 0.f;
        for (int cc = 0; cc < NCHUNK_C; ++cc) {
            const int cbb = bb * NCHUNK_C + cc;
            const size_t off = ((size_t)cbb * NST + nn) * DIN + dd;
            const float he = hc[off];
            const float pa = __expf(A2 * sdtg[(size_t)cbb * DIN + dd]);
            hc[off] = h;                         // h entering chunk cc
            h = fmaf(pa, h, he);
        }
    }
    __threadfence();
    grid.sync();

    // ---- P4: replay with h-init, dt from LDS, emit ysb ----
    {
        float h[NST];
        #pragma unroll
        for (int n = 0; n < NST; ++n)
            h[n] = hc[((size_t)cb * NST + n) * DIN + d];
        const float Dv = Dp[d];

        for (int tl = 0; tl < CLEN_C; ++tl) {
            const float dtv = bf2f(shm.s.dtc[tl * 256 + tid]);
            const float uv  = bf2f(yb[tbase + (size_t)tl * DIN]);
            const float cu = dtv * uv;
            float yacc = 0.f;
            #pragma unroll
            for (int n = 0; n < NST; ++n) {
                const float a = __expf(A2r[n] * dtv);
                h[n] = fmaf(a, h[n], cu * shm.s.Bsc[tl][n]);
                yacc = fmaf(h[n], shm.s.Csc[tl][n], yacc);
            }
            ysb[tbase + (size_t)tl * DIN] = f2bf(fmaf(Dv, uv, yacc));
        }
    }
}

// ---------------- launcher ----------------
extern "C" void kernel_launch(void* const* d_in, const int* in_sizes, int n_in,
                              void* d_out, int out_size, void* d_ws, size_t ws_size,
                              hipStream_t stream)
{
    const float* x       = (const float*)d_in[0];
    const float* in_g1   = (const float*)d_in[1];
    const float* in_g2   = (const float*)d_in[2];
    const float* x_g1    = (const float*)d_in[3];
    const float* x_g2    = (const float*)d_in[4];
    const float* dt_g1   = (const float*)d_in[5];
    const float* dt_g2   = (const float*)d_in[6];
    const float* out_g1  = (const float*)d_in[7];
    const float* out_g2  = (const float*)d_in[8];
    const float* filt    = (const float*)d_in[9];
    const float* bias    = (const float*)d_in[10];
    const float* A_log   = (const float*)d_in[11];
    const float* Dp      = (const float*)d_in[12];

    float* ws     = (float*)d_ws;
    u16*   W_inT  = (u16*)(ws + OFF_WINT);
    u16*   W_outT = (u16*)(ws + OFF_WOUTT);
    u16*   W_xT   = (u16*)(ws + OFF_WXT);
    u16*   W_dtT  = (u16*)(ws + OFF_WDTT);
    float* A2t    = ws + OFF_A2T;
    u16*   xb     = (u16*)(ws + OFF_XB);
    u16*   xzb    = (u16*)(ws + OFF_XZB);
    u16*   yb     = (u16*)(ws + OFF_YB);
    float* part   = ws + OFF_PART;
    float* dtBC   = ws + OFF_DTBC;
    u16*   dtun_b = (u16*)(ws + OFF_DTUNB);
    u16*   dtb    = (u16*)(ws + OFF_DTB);
    u16*   ysb    = (u16*)(ws + OFF_YSB);
    float* hc     = ws + OFF_HC;
    float* sdtg   = ws + OFF_SDT;

    // 1) all prep in one launch
    mega_prep<<<9472, 256, 0, stream>>>(
        in_g1, in_g2, W_inT, out_g1, out_g2, W_outT,
        x_g1, x_g2, W_xT, dt_g1, dt_g2, W_dtT,
        x, xb, A_log, A2t);

    // 2) xz = x @ W_in  (M=2048, N=4096, K=1024), BK=64 -> bf16
    gemm_bf16<128, 64, 1><<<dim3(32, 16, 1), 256, 0, stream>>>(
        xb, W_inT, xzb, EE, 4096, EE, 0);

    // 3) y = silu(conv(xc) + bias) * z  -> bf16
    conv_gate<<<(BL * DIN / 8 + 255) / 256, 256, 0, stream>>>(xzb, filt, bias, yb);

    // 4) dtBC partials = y @ W_x (M=2048, N=128, K=2048), split-K z=16
    gemm_bf16<128, 64, 0><<<dim3(1, 16, 16), 256, 0, stream>>>(
        yb, W_xT, part, DIN, 128, 128, (size_t)BL * 128);

    // 5) mid-section: try cooperative (256 blocks); fall back to 5 kernels.
    {
        const float* part_c = part;
        void* args[] = { (void*)&part_c, (void*)&dtBC, (void*)&dtun_b,
                         (void*)&W_dtT, (void*)&dtb, (void*)&yb, (void*)&A2t,
                         (void*)&hc, (void*)&sdtg, (void*)&Dp, (void*)&ysb };
        hipError_t ce = hipLaunchCooperativeKernel((const void*)coop_mid, dim3(256),
                                                   dim3(256), args, 0, stream);
        if (ce != hipSuccess) {
            (void)hipGetLastError();   // clear sticky error; fall back (R6 path)
            reduce_dtbc<<<(BL * 96 + 255) / 256, 256, 0, stream>>>(part, dtBC, dtun_b);
            gemm_bf16<128, 64, 2><<<dim3(16, 16, 1), 256, 0, stream>>>(
                dtun_b, W_dtT, dtb, 64, DIN, 64, 0);
            scan_phase_a<<<dim3(DIN / 256, NCHUNK, BB_), 256, 0, stream>>>(dtb, yb, dtBC, A2t, hc, sdtg);
            scan_phase_b<<<(BB_ * NST * DIN) / 256, 256, 0, stream>>>(A2t, sdtg, hc);
            scan_phase_c<<<dim3(DIN / 256, NCHUNK, BB_), 256, 0, stream>>>(dtb, yb, dtBC, A2t, hc, Dp, ysb);
        }
    }

    // 6) out = ssm @ W_out (M=2048, N=1024, K=2048), split-K z=2
    gemm_bf16<64, 64, 0><<<dim3(16, 16, 2), 256, 0, stream>>>(
        ysb, W_outT, part, DIN, EE, EE, (size_t)BL * EE);
    reduce_out<<<(BL * EE / 4) / 256, 256, 0, stream>>>(part, (float*)d_out);
}

// Round 9
// 240.834 us; speedup vs baseline: 1.8902x; 1.8902x over previous
//
#include <hip/hip_runtime.h>
#include <hip/hip_bf16.h>
#include <cstdint>
#include <cstddef>

// Problem constants
#define EE    1024
#define DIN   2048
#define NST   16
#define DTR   64
#define BB_   2
#define LL    1024
#define BL    (BB_*LL)        // 2048 tokens
#define NCHUNK 32
#define CLEN   32             // 1024 / 32
#define RTT   16              // TT rank (all four factor pairs)

typedef unsigned short u16;
typedef unsigned int   u32;

// ---------------- workspace layout (in floats) ----------------
static constexpr size_t OFF_WINT  = 0;                   // bf16 [4096][1024]
static constexpr size_t OFF_WOUTT = 2097152;             // bf16 [1024][2048]
static constexpr size_t OFF_WXT   = 3145728;             // bf16 [128][2048] rows>=96 zero
static constexpr size_t OFF_WDTT  = 3276800;             // bf16 [2048][64]
static constexpr size_t OFF_A2T   = 3342336;             // f32  [16][2048]
static constexpr size_t OFF_XB    = 3375104;             // bf16 [2048][1024]
static constexpr size_t OFF_XZB   = 4423680;             // bf16 [2048][4096]
static constexpr size_t OFF_YB    = 8617984;             // bf16 [2048][2048]
static constexpr size_t OFF_PART  = 10715136;            // f32  [16][2048][128] ; reused: GEMM4 partials [2][2048][1024]
static constexpr size_t OFF_DTBC  = 14909440;            // f32  [2048][96]
static constexpr size_t OFF_DTUNB = 15106048;            // bf16 [2048][64]
static constexpr size_t OFF_DTB   = 15171584;            // bf16 [2048][2048] (dt)
static constexpr size_t OFF_YSB   = 17268736;            // bf16 [2048][2048]
static constexpr size_t OFF_HC    = 19365888;            // f32  [2*32][16][2048] chunk-end states
static constexpr size_t OFF_SDT   = 21463040;            // f32  [2*32][2048]

// ---------------- helpers ----------------
__device__ __forceinline__ u16 f2bf(float f) {   // RNE f32->bf16
    u32 u = __float_as_uint(f);
    u += 0x7fffu + ((u >> 16) & 1u);
    return (u16)(u >> 16);
}
__device__ __forceinline__ float bf2f(u16 v) {
    return __uint_as_float((u32)v << 16);
}

__device__ __forceinline__ void async_copy16(const void* g, void* l) {
    __builtin_amdgcn_global_load_lds((const __attribute__((address_space(1))) u32*)g,
                                     (__attribute__((address_space(3))) u32*)l,
                                     16, 0, 0);
}

__device__ __forceinline__ float softplusf(float v) {
    return fmaxf(v, 0.f) + log1pf(__expf(-fabsf(v)));
}

// ---------------- fused prep: 4 TT builds + x->bf16 + A2t ----------------
__device__ void tt_part(const float* __restrict__ g1, const float* __restrict__ g2,
                        u16* __restrict__ Wt, int m1, int n1, int m2, int n2,
                        int c, int crows, float* g1col, float* g2col)
{
    const int rowsW = m1 * m2;
    if (c >= crows) {                      // zero padding rows (GEMM2 N-pad)
        for (int k = threadIdx.x; k < rowsW; k += 256)
            Wt[(size_t)c * rowsW + k] = 0;
        return;
    }
    const int i = c / n2;
    const int j = c - i * n2;

    for (int e = threadIdx.x; e < m1 * RTT; e += 256) {
        const int a = e >> 4, rr = e & 15;
        g1col[e] = g1[(size_t)(a * n1 + i) * RTT + rr];
    }
    for (int e = threadIdx.x; e < RTT * m2; e += 256) {
        const int rr = e / m2, bb = e - rr * m2;
        g2col[e] = g2[(size_t)(rr * m2 + bb) * n2 + j];
    }
    __syncthreads();

    for (int k = threadIdx.x; k < rowsW; k += 256) {
        const int a  = k / m2;
        const int bb = k - a * m2;
        const float* gp = g1col + a * RTT;
        float s = 0.f;
        #pragma unroll
        for (int rr = 0; rr < RTT; ++rr)
            s = fmaf(gp[rr], g2col[rr * m2 + bb], s);
        Wt[(size_t)c * rowsW + k] = f2bf(s);
    }
}

__global__ __launch_bounds__(256) void mega_prep(
    const float* __restrict__ in_g1, const float* __restrict__ in_g2, u16* __restrict__ W_inT,
    const float* __restrict__ out_g1, const float* __restrict__ out_g2, u16* __restrict__ W_outT,
    const float* __restrict__ x_g1, const float* __restrict__ x_g2, u16* __restrict__ W_xT,
    const float* __restrict__ dt_g1, const float* __restrict__ dt_g2, u16* __restrict__ W_dtT,
    const float* __restrict__ x, u16* __restrict__ xb,
    const float* __restrict__ A_log, float* __restrict__ A2t)
{
    __shared__ float g1col[32 * RTT];
    __shared__ float g2col[RTT * 64];
    const int blk = blockIdx.x;
    if (blk < 4096) {
        tt_part(in_g1, in_g2, W_inT, 32, 64, 32, 64, blk, 4096, g1col, g2col);
    } else if (blk < 5120) {
        tt_part(out_g1, out_g2, W_outT, 32, 32, 64, 32, blk - 4096, 1024, g1col, g2col);
    } else if (blk < 5248) {
        tt_part(x_g1, x_g2, W_xT, 32, 8, 64, 12, blk - 5120, 96, g1col, g2col);
    } else if (blk < 7296) {
        tt_part(dt_g1, dt_g2, W_dtT, 8, 32, 8, 64, blk - 5248, 2048, g1col, g2col);
    } else if (blk < 9344) {
        const int i = (blk - 7296) * 256 + threadIdx.x;   // over BL*EE/4
        float4 v = ((const float4*)x)[i];
        ushort4 o;
        o.x = f2bf(v.x); o.y = f2bf(v.y); o.z = f2bf(v.z); o.w = f2bf(v.w);
        ((ushort4*)xb)[i] = o;
    } else {
        const int idx = (blk - 9344) * 256 + threadIdx.x; // over DIN*NST
        const int d = idx >> 4, n = idx & 15;
        A2t[n * DIN + d] = -expf(A_log[idx]);
    }
}

// ---------------- bf16 MFMA GEMM (templated BN / BK / output mode) ----------------
// C = A[M,K] @ Bt[N,K]^T. A/Bt row-major bf16 (row stride K). BM=128, BK=64.
// XOR swizzle on 16B k-slots -> ds_read_b128 2-way (free, m136),
// global_load_lds lane-contiguity kept. Split-K via blockIdx.z / czstride.
// OUT: 0 = f32 store, 1 = bf16, 2 = softplus+bf16.
typedef __attribute__((ext_vector_type(8))) short bf16x8;
typedef __attribute__((ext_vector_type(4))) float floatx4;

template<int BN, int BK, int OUT>
__global__ __launch_bounds__(256) void gemm_bf16(
    const u16* __restrict__ A, const u16* __restrict__ Bt, void* __restrict__ Cout,
    int K, int ldc, int kchunk, size_t czstride)
{
    constexpr int BM   = 128;
    constexpr int NT   = BN / 32;
    constexpr int SLOT = BK / 8;
    constexpr int CR   = 64 / SLOT;
    constexpr int NACH = BM / CR / 4;
    constexpr int NBCH = BN / CR / 4;
    constexpr int KG   = BK / 32;
    __shared__ u16 As[BM * BK];
    __shared__ u16 Bs[BN * BK];

    const int tid  = threadIdx.x;
    const int w    = tid >> 6;
    const int lane = tid & 63;
    const int wm   = w & 1, wn = w >> 1;
    const int row0 = blockIdx.y * BM;
    const int col0 = blockIdx.x * BN;
    const int kbeg = blockIdx.z * kchunk;

    const int srow = lane / SLOT;
    const int kqp  = lane % SLOT;
    const u16* ga[NACH]; u16* la[NACH];
    #pragma unroll
    for (int i = 0; i < NACH; ++i) {
        const int c  = w * NACH + i;
        const int r  = c * CR + srow;
        const int kq = kqp ^ ((r >> 1) & (SLOT - 1));
        ga[i] = A + (size_t)(row0 + r) * K + kbeg + kq * 8;
        la[i] = &As[c * CR * BK];
    }
    const u16* gb[NBCH]; u16* lb[NBCH];
    #pragma unroll
    for (int i = 0; i < NBCH; ++i) {
        const int c  = w * NBCH + i;
        const int r  = c * CR + srow;
        const int kq = kqp ^ ((r >> 1) & (SLOT - 1));
        gb[i] = Bt + (size_t)(col0 + r) * K + kbeg + kq * 8;
        lb[i] = &Bs[c * CR * BK];
    }

    const int q = lane >> 4, l15 = lane & 15;
    int a_off[4][KG], b_off[NT][KG];
    #pragma unroll
    for (int mt = 0; mt < 4; ++mt) {
        const int r = wm * 64 + mt * 16 + l15;
        const int m = (r >> 1) & (SLOT - 1);
        #pragma unroll
        for (int kk = 0; kk < KG; ++kk)
            a_off[mt][kk] = r * BK + ((kk * 4 + q) ^ m) * 8;
    }
    #pragma unroll
    for (int nt = 0; nt < NT; ++nt) {
        const int r = wn * (BN / 2) + nt * 16 + l15;
        const int m = (r >> 1) & (SLOT - 1);
        #pragma unroll
        for (int kk = 0; kk < KG; ++kk)
            b_off[nt][kk] = r * BK + ((kk * 4 + q) ^ m) * 8;
    }

    floatx4 acc[4][NT];
    #pragma unroll
    for (int mt = 0; mt < 4; ++mt)
        #pragma unroll
        for (int nt = 0; nt < NT; ++nt)
            acc[mt][nt] = (floatx4){0.f, 0.f, 0.f, 0.f};

    for (int k0 = 0; k0 < kchunk; k0 += BK) {
        #pragma unroll
        for (int i = 0; i < NACH; ++i) { async_copy16(ga[i], la[i]); ga[i] += BK; }
        #pragma unroll
        for (int i = 0; i < NBCH; ++i) { async_copy16(gb[i], lb[i]); gb[i] += BK; }
        __syncthreads();

        bf16x8 af[4][KG], bfv[NT][KG];
        #pragma unroll
        for (int mt = 0; mt < 4; ++mt)
            #pragma unroll
            for (int kk = 0; kk < KG; ++kk)
                af[mt][kk] = *(const bf16x8*)&As[a_off[mt][kk]];
        #pragma unroll
        for (int nt = 0; nt < NT; ++nt)
            #pragma unroll
            for (int kk = 0; kk < KG; ++kk)
                bfv[nt][kk] = *(const bf16x8*)&Bs[b_off[nt][kk]];

        #pragma unroll
        for (int kk = 0; kk < KG; ++kk)
            #pragma unroll
            for (int mt = 0; mt < 4; ++mt)
                #pragma unroll
                for (int nt = 0; nt < NT; ++nt)
                    acc[mt][nt] = __builtin_amdgcn_mfma_f32_16x16x32_bf16(
                        af[mt][kk], bfv[nt][kk], acc[mt][nt], 0, 0, 0);

        __syncthreads();
    }

    // epilogue: C/D layout col=lane&15, row=(lane>>4)*4+reg  [verified m89/m91]
    #pragma unroll
    for (int mt = 0; mt < 4; ++mt) {
        const int row = row0 + wm * 64 + mt * 16 + q * 4;
        #pragma unroll
        for (int nt = 0; nt < NT; ++nt) {
            const int col = col0 + wn * (BN / 2) + nt * 16 + l15;
            #pragma unroll
            for (int r = 0; r < 4; ++r) {
                const float v = acc[mt][nt][r];
                if constexpr (OUT == 0) {
                    ((float*)Cout)[(size_t)blockIdx.z * czstride + (size_t)(row + r) * ldc + col] = v;
                } else if constexpr (OUT == 1) {
                    ((u16*)Cout)[(size_t)(row + r) * ldc + col] = f2bf(v);
                } else {
                    ((u16*)Cout)[(size_t)(row + r) * ldc + col] = f2bf(softplusf(v));
                }
            }
        }
    }
}

// reduce GEMM2 split-K partials: dtBC[row][col<96] = sum_z part[z][row][col];
// also emit dt_un (cols 0..63) as bf16 for GEMM3.
__global__ __launch_bounds__(256) void reduce_dtbc(
    const float* __restrict__ part, float* __restrict__ dtBC, u16* __restrict__ dtun_b)
{
    int idx = blockIdx.x * 256 + threadIdx.x;
    if (idx >= BL * 96) return;
    const int row = idx / 96;
    const int col = idx - row * 96;
    float s = 0.f;
    #pragma unroll
    for (int z = 0; z < 16; ++z)
        s += part[(size_t)z * BL * 128 + (size_t)row * 128 + col];
    dtBC[idx] = s;
    if (col < 64) dtun_b[(size_t)row * 64 + col] = f2bf(s);
}

// reduce GEMM4 split-K partials (z=2) -> f32 d_out, float4-wide
__global__ __launch_bounds__(256) void reduce_out(
    const float* __restrict__ part, float* __restrict__ out)
{
    const int idx = blockIdx.x * 256 + threadIdx.x;   // over BL*EE/4
    const float4 a = ((const float4*)part)[idx];
    const float4 b = ((const float4*)part)[idx + BL * EE / 4];
    float4 o;
    o.x = a.x + b.x; o.y = a.y + b.y; o.z = a.z + b.z; o.w = a.w + b.w;
    ((float4*)out)[idx] = o;
}

// ---------------- conv (depthwise K=4, SAME pad_lo=1) + SiLU + gate, bf16, 8-wide ----------------
typedef __attribute__((ext_vector_type(8))) unsigned short ushortx8;

__global__ __launch_bounds__(256) void conv_gate(
    const u16* __restrict__ xzb, const float* __restrict__ filt,
    const float* __restrict__ bias, u16* __restrict__ yb)
{
    int idx = blockIdx.x * blockDim.x + threadIdx.x;   // over BL*DIN/8
    if (idx >= BL * DIN / 8) return;
    const int d  = (idx % (DIN / 8)) * 8;
    const int bt = idx / (DIN / 8);
    const int b  = bt >> 10;
    const int t  = bt & 1023;

    float acc[8];
    #pragma unroll
    for (int j = 0; j < 8; ++j) acc[j] = bias[d + j];
    #pragma unroll
    for (int k = 0; k < 4; ++k) {
        const int tt = t + k - 1;
        if ((unsigned)tt < (unsigned)LL) {
            const ushortx8 xc = *(const ushortx8*)(xzb + (size_t)(b * LL + tt) * (2 * DIN) + d);
            #pragma unroll
            for (int j = 0; j < 8; ++j)
                acc[j] = fmaf(bf2f(xc[j]), filt[(size_t)k * DIN + d + j], acc[j]);
        }
    }
    const ushortx8 z = *(const ushortx8*)(xzb + (size_t)bt * (2 * DIN) + DIN + d);
    ushortx8 o;
    #pragma unroll
    for (int j = 0; j < 8; ++j)
        o[j] = f2bf(acc[j] / (1.f + __expf(-acc[j])) * bf2f(z[j]));
    *(ushortx8*)(yb + (size_t)bt * DIN + d) = o;
}

// ---------------- SSM chunked scan (dt, u bf16; NCHUNK=32) ----------------
// Phase A: chunk-local scan from h=0 -> hend[b][c][n][d], sdt[b][c][d]
__global__ __launch_bounds__(256) void scan_phase_a(
    const u16* __restrict__ dt, const u16* __restrict__ u,
    const float* __restrict__ dtBC, const float* __restrict__ A2t,
    float* __restrict__ hend, float* __restrict__ sdtbuf)
{
    const int d = blockIdx.x * 256 + threadIdx.x;
    const int c = blockIdx.y;
    const int b = blockIdx.z;

    __shared__ float Bs[CLEN][NST];
    for (int e = threadIdx.x; e < CLEN * NST; e += 256) {
        const int tl = e >> 4, n = e & 15;
        Bs[tl][n] = dtBC[(size_t)(b * LL + c * CLEN + tl) * 96 + 64 + n];
    }
    __syncthreads();

    float A2r[NST];
    #pragma unroll
    for (int n = 0; n < NST; ++n) A2r[n] = A2t[n * DIN + d];

    float h[NST] = {};
    float sdt = 0.f;
    const size_t tbase = (size_t)(b * LL + c * CLEN) * DIN + d;
    for (int tl = 0; tl < CLEN; ++tl) {
        const float dtv = bf2f(dt[tbase + (size_t)tl * DIN]);
        const float uv  = bf2f(u [tbase + (size_t)tl * DIN]);
        sdt += dtv;
        const float cu = dtv * uv;
        #pragma unroll
        for (int n = 0; n < NST; ++n) {
            const float a = __expf(A2r[n] * dtv);
            h[n] = fmaf(a, h[n], cu * Bs[tl][n]);
        }
    }
    const int cb = b * NCHUNK + c;
    #pragma unroll
    for (int n = 0; n < NST; ++n)
        hend[((size_t)cb * NST + n) * DIN + d] = h[n];
    sdtbuf[(size_t)cb * DIN + d] = sdt;
}

// Phase BC (scan_b folded into scan_c): each block computes its own h-init
// prefix from hend/sdt (same recurrence & order as the old phase B -> bit-
// identical), then replays the chunk emitting ysb. Saves one dispatch and
// the in-place hc rewrite round-trip.  [R8 lesson: grid.sync fusion costs
// ~60us/sync on this stack — dispatch boundaries are the cheap sync.]
__global__ __launch_bounds__(256) void scan_phase_bc(
    const u16* __restrict__ dt, const u16* __restrict__ u,
    const float* __restrict__ dtBC, const float* __restrict__ A2t,
    const float* __restrict__ hend, const float* __restrict__ sdtbuf,
    const float* __restrict__ Dp, u16* __restrict__ ysb)
{
    const int d = blockIdx.x * 256 + threadIdx.x;
    const int c = blockIdx.y;
    const int b = blockIdx.z;

    __shared__ float Bs[CLEN][NST];
    __shared__ float Cs[CLEN][NST];
    for (int e = threadIdx.x; e < CLEN * NST; e += 256) {
        const int tl = e >> 4, n = e & 15;
        const size_t base = (size_t)(b * LL + c * CLEN + tl) * 96;
        Bs[tl][n] = dtBC[base + 64 + n];
        Cs[tl][n] = dtBC[base + 80 + n];
    }
    __syncthreads();

    float A2r[NST];
    #pragma unroll
    for (int n = 0; n < NST; ++n) A2r[n] = A2t[n * DIN + d];

    // h-init prefix over chunks 0..c-1 (identical op order to old phase B)
    float h[NST] = {};
    for (int cc = 0; cc < c; ++cc) {
        const int cbb = b * NCHUNK + cc;
        const float sdtv = sdtbuf[(size_t)cbb * DIN + d];
        #pragma unroll
        for (int n = 0; n < NST; ++n) {
            const float pa = __expf(A2r[n] * sdtv);
            h[n] = fmaf(pa, h[n], hend[((size_t)cbb * NST + n) * DIN + d]);
        }
    }
    const float Dv = Dp[d];

    const size_t tbase = (size_t)(b * LL + c * CLEN) * DIN + d;
    for (int tl = 0; tl < CLEN; ++tl) {
        const float dtv = bf2f(dt[tbase + (size_t)tl * DIN]);
        const float uv  = bf2f(u [tbase + (size_t)tl * DIN]);
        const float cu = dtv * uv;
        float yacc = 0.f;
        #pragma unroll
        for (int n = 0; n < NST; ++n) {
            const float a = __expf(A2r[n] * dtv);
            h[n] = fmaf(a, h[n], cu * Bs[tl][n]);
            yacc = fmaf(h[n], Cs[tl][n], yacc);
        }
        ysb[tbase + (size_t)tl * DIN] = f2bf(fmaf(Dv, uv, yacc));
    }
}

// ---------------- launcher ----------------
extern "C" void kernel_launch(void* const* d_in, const int* in_sizes, int n_in,
                              void* d_out, int out_size, void* d_ws, size_t ws_size,
                              hipStream_t stream)
{
    const float* x       = (const float*)d_in[0];
    const float* in_g1   = (const float*)d_in[1];
    const float* in_g2   = (const float*)d_in[2];
    const float* x_g1    = (const float*)d_in[3];
    const float* x_g2    = (const float*)d_in[4];
    const float* dt_g1   = (const float*)d_in[5];
    const float* dt_g2   = (const float*)d_in[6];
    const float* out_g1  = (const float*)d_in[7];
    const float* out_g2  = (const float*)d_in[8];
    const float* filt    = (const float*)d_in[9];
    const float* bias    = (const float*)d_in[10];
    const float* A_log   = (const float*)d_in[11];
    const float* Dp      = (const float*)d_in[12];

    float* ws     = (float*)d_ws;
    u16*   W_inT  = (u16*)(ws + OFF_WINT);
    u16*   W_outT = (u16*)(ws + OFF_WOUTT);
    u16*   W_xT   = (u16*)(ws + OFF_WXT);
    u16*   W_dtT  = (u16*)(ws + OFF_WDTT);
    float* A2t    = ws + OFF_A2T;
    u16*   xb     = (u16*)(ws + OFF_XB);
    u16*   xzb    = (u16*)(ws + OFF_XZB);
    u16*   yb     = (u16*)(ws + OFF_YB);
    float* part   = ws + OFF_PART;
    float* dtBC   = ws + OFF_DTBC;
    u16*   dtun_b = (u16*)(ws + OFF_DTUNB);
    u16*   dtb    = (u16*)(ws + OFF_DTB);
    u16*   ysb    = (u16*)(ws + OFF_YSB);
    float* hc     = ws + OFF_HC;
    float* sdtg   = ws + OFF_SDT;

    // 1) all prep in one launch: W_inT, W_outT, W_xT, W_dtT, x->bf16, A2t
    mega_prep<<<9472, 256, 0, stream>>>(
        in_g1, in_g2, W_inT, out_g1, out_g2, W_outT,
        x_g1, x_g2, W_xT, dt_g1, dt_g2, W_dtT,
        x, xb, A_log, A2t);

    // 2) xz = x @ W_in  (M=2048, N=4096, K=1024), BK=64 -> bf16
    gemm_bf16<128, 64, 1><<<dim3(32, 16, 1), 256, 0, stream>>>(
        xb, W_inT, xzb, EE, 4096, EE, 0);

    // 3) y = silu(conv(xc) + bias) * z  -> bf16, 8-wide
    conv_gate<<<(BL * DIN / 8 + 255) / 256, 256, 0, stream>>>(xzb, filt, bias, yb);

    // 4) dtBC partials = y @ W_x (M=2048, N=128, K=2048), split-K z=16
    gemm_bf16<128, 64, 0><<<dim3(1, 16, 16), 256, 0, stream>>>(
        yb, W_xT, part, DIN, 128, 128, (size_t)BL * 128);
    reduce_dtbc<<<(BL * 96 + 255) / 256, 256, 0, stream>>>(part, dtBC, dtun_b);

    // 5) dt = softplus(dt_un @ W_dt) (M=2048, N=2048, K=64) single-step -> bf16
    gemm_bf16<128, 64, 2><<<dim3(16, 16, 1), 256, 0, stream>>>(
        dtun_b, W_dtT, dtb, 64, DIN, 64, 0);

    // 6) SSM chunked scan, NCHUNK=32 (512 blocks = 2/CU), phase B folded into C
    scan_phase_a<<<dim3(DIN / 256, NCHUNK, BB_), 256, 0, stream>>>(dtb, yb, dtBC, A2t, hc, sdtg);
    scan_phase_bc<<<dim3(DIN / 256, NCHUNK, BB_), 256, 0, stream>>>(dtb, yb, dtBC, A2t, hc, sdtg, Dp, ysb);

    // 7) out = ssm @ W_out (M=2048, N=1024, K=2048), split-K z=2 (512 blocks)
    gemm_bf16<64, 64, 0><<<dim3(16, 16, 2), 256, 0, stream>>>(
        ysb, W_outT, part, DIN, EE, EE, (size_t)BL * EE);
    reduce_out<<<(BL * EE / 4) / 256, 256, 0, stream>>>(part, (float*)d_out);
}